// Round 1
// baseline (762.946 us; speedup 1.0000x reference)
//
#include <hip/hip_runtime.h>

#define BB 16
#define C 192
#define COUT 384
#define H 64
#define W 64
#define HW (H * W)
#define KK 9
#define OFFC 18

// ---------------------------------------------------------------------------
// Kernel A: offset conv (3x3, pad 1) -> offs[B][18][H][W]
// block = 256 threads = 4 rows x 64 cols of one image; grid = B * H/4 = 256
// ---------------------------------------------------------------------------
__global__ __launch_bounds__(256) void offset_conv(
    const float* __restrict__ x, const float* __restrict__ w_off,
    const float* __restrict__ b_off, float* __restrict__ offs) {
  int blk = blockIdx.x;
  int b = blk / (H / 4);
  int h0 = (blk % (H / 4)) * 4;
  int tid = threadIdx.x;
  int r = tid >> 6;
  int w = tid & 63;
  int h = h0 + r;

  __shared__ float sw[OFFC][16][KK];  // 10368 B

  float acc[OFFC];
#pragma unroll
  for (int o = 0; o < OFFC; ++o) acc[o] = b_off[o];

  const float* xb = x + (size_t)b * C * HW;

  for (int c0 = 0; c0 < C; c0 += 16) {
    __syncthreads();
    for (int i = tid; i < OFFC * 16 * KK; i += 256) {
      int o = i / (16 * KK);
      int rem = i % (16 * KK);
      int cc = rem / KK;
      int kk = rem % KK;
      sw[o][cc][kk] = w_off[((size_t)o * C + (c0 + cc)) * KK + kk];
    }
    __syncthreads();
    for (int cc = 0; cc < 16; ++cc) {
      const float* xc = xb + (size_t)(c0 + cc) * HW;
      float xv[KK];
#pragma unroll
      for (int di = 0; di < 3; ++di) {
        int yy = h + di - 1;
#pragma unroll
        for (int dj = 0; dj < 3; ++dj) {
          int xx = w + dj - 1;
          bool ok = (yy >= 0) && (yy < H) && (xx >= 0) && (xx < W);
          xv[di * 3 + dj] = ok ? xc[yy * W + xx] : 0.f;
        }
      }
#pragma unroll
      for (int o = 0; o < OFFC; ++o) {
        float s0 = 0.f;
#pragma unroll
        for (int kk = 0; kk < KK; ++kk) s0 += xv[kk] * sw[o][cc][kk];
        acc[o] += s0;
      }
    }
  }
  size_t base = (size_t)b * OFFC * HW + (size_t)h * W + w;
#pragma unroll
  for (int o = 0; o < OFFC; ++o) offs[base + (size_t)o * HW] = acc[o];
}

// ---------------------------------------------------------------------------
// Kernel B: bilinear sample + depthwise -> dwout[B][C][H][W]
// block = 256 threads = 4 rows x 64 cols; 4-way channel split (48 ch each)
// grid = B * 16 * 4 = 1024
// ---------------------------------------------------------------------------
__global__ __launch_bounds__(256) void sample_dw(
    const float* __restrict__ x, const float* __restrict__ offs,
    const float* __restrict__ w_dw, float* __restrict__ dwout) {
  int blk = blockIdx.x;
  int csplit = blk & 3;
  int rowtile = (blk >> 2) & 15;
  int b = blk >> 6;
  int tid = threadIdx.x;
  int r = tid >> 6;
  int w = tid & 63;
  int h = rowtile * 4 + r;

  const float* ob = offs + (size_t)b * OFFC * HW + (size_t)h * W + w;

  int addr[KK][4];
  float wt[KK][4];
#pragma unroll
  for (int k = 0; k < KK; ++k) {
    int ki = k / 3, kj = k % 3;
    float oy = ob[(size_t)(2 * k) * HW];
    float ox = ob[(size_t)(2 * k + 1) * HW];
    float py = (float)(h - 1 + ki) + oy;
    float px = (float)(w - 1 + kj) + ox;
    float y0f = floorf(py), x0f = floorf(px);
    float dy = py - y0f, dx = px - x0f;
    int y0 = (int)y0f, x0 = (int)x0f;
    int y1 = y0 + 1, x1 = x0 + 1;
    float vy0 = (y0 >= 0 && y0 < H) ? 1.f : 0.f;
    float vy1 = (y1 >= 0 && y1 < H) ? 1.f : 0.f;
    float vx0 = (x0 >= 0 && x0 < W) ? 1.f : 0.f;
    float vx1 = (x1 >= 0 && x1 < W) ? 1.f : 0.f;
    int y0c = min(max(y0, 0), H - 1), y1c = min(max(y1, 0), H - 1);
    int x0c = min(max(x0, 0), W - 1), x1c = min(max(x1, 0), W - 1);
    addr[k][0] = y0c * W + x0c;
    addr[k][1] = y0c * W + x1c;
    addr[k][2] = y1c * W + x0c;
    addr[k][3] = y1c * W + x1c;
    wt[k][0] = (1.f - dy) * (1.f - dx) * vy0 * vx0;
    wt[k][1] = (1.f - dy) * dx * vy0 * vx1;
    wt[k][2] = dy * (1.f - dx) * vy1 * vx0;
    wt[k][3] = dy * dx * vy1 * vx1;
  }

  const int c0 = csplit * 48;
  const float* xb = x + ((size_t)b * C + c0) * HW;
  float* db = dwout + ((size_t)b * C + c0) * HW + (size_t)h * W + w;
  const float* wd = w_dw + (size_t)c0 * KK;
  for (int c = 0; c < 48; ++c) {
    const float* xc = xb + (size_t)c * HW;
    float acc = 0.f;
#pragma unroll
    for (int k = 0; k < KK; ++k) {
      float v = wt[k][0] * xc[addr[k][0]] + wt[k][1] * xc[addr[k][1]] +
                wt[k][2] * xc[addr[k][2]] + wt[k][3] * xc[addr[k][3]];
      acc += wd[c * KK + k] * v;
    }
    db[(size_t)c * HW] = acc;
  }
}

// ---------------------------------------------------------------------------
// Kernel C: pointwise 1x1 conv as tiled GEMM: out[b][o][p] = sum_c dw*w_pw
// M=384 (o), N=4096 (p), K=192 (c) per batch. 64x64x16 tiles, 256 thr, 4x4.
// grid = B * 6 * 64 = 6144
// ---------------------------------------------------------------------------
__global__ __launch_bounds__(256) void pointwise(
    const float* __restrict__ dw, const float* __restrict__ w_pw,
    float* __restrict__ out) {
  int blk = blockIdx.x;
  int ntile = blk & 63;
  int mtile = (blk >> 6) % 6;
  int b = blk / (6 * 64);
  int n0 = ntile * 64;
  int m0 = mtile * 64;
  int tid = threadIdx.x;
  int tx = tid & 15, ty = tid >> 4;

  __shared__ float As[16][64];
  __shared__ float Bs[16][64];

  const float* dwb = dw + (size_t)b * C * HW;
  float acc[4][4] = {};

  for (int k0 = 0; k0 < C; k0 += 16) {
    __syncthreads();
    {
      int i = tid * 4;
      int m = i >> 4;
      int kk = i & 15;
      float4 v = *(const float4*)(w_pw + (size_t)(m0 + m) * C + k0 + kk);
      As[kk + 0][m] = v.x;
      As[kk + 1][m] = v.y;
      As[kk + 2][m] = v.z;
      As[kk + 3][m] = v.w;
      int kk2 = tid >> 4;
      int n = (tid & 15) * 4;
      float4 u = *(const float4*)(dwb + (size_t)(k0 + kk2) * HW + n0 + n);
      *(float4*)&Bs[kk2][n] = u;
    }
    __syncthreads();
#pragma unroll
    for (int kk = 0; kk < 16; ++kk) {
      float a[4], bb[4];
#pragma unroll
      for (int j = 0; j < 4; ++j) a[j] = As[kk][ty * 4 + j];
#pragma unroll
      for (int j = 0; j < 4; ++j) bb[j] = Bs[kk][tx * 4 + j];
#pragma unroll
      for (int i2 = 0; i2 < 4; ++i2)
#pragma unroll
        for (int j2 = 0; j2 < 4; ++j2) acc[i2][j2] += a[i2] * bb[j2];
    }
  }
  float* obp = out + ((size_t)b * COUT + m0 + ty * 4) * HW + n0 + tx * 4;
#pragma unroll
  for (int i2 = 0; i2 < 4; ++i2)
    *(float4*)(obp + (size_t)i2 * HW) =
        make_float4(acc[i2][0], acc[i2][1], acc[i2][2], acc[i2][3]);
}

// ---------------------------------------------------------------------------
extern "C" void kernel_launch(void* const* d_in, const int* in_sizes, int n_in,
                              void* d_out, int out_size, void* d_ws,
                              size_t ws_size, hipStream_t stream) {
  const float* x = (const float*)d_in[0];
  const float* w_off = (const float*)d_in[1];
  const float* b_off = (const float*)d_in[2];
  const float* w_dw = (const float*)d_in[3];
  const float* w_pw = (const float*)d_in[4];
  float* out = (float*)d_out;

  float* offs = (float*)d_ws;                                   // 16*18*4096 f32
  float* dwbuf = (float*)((char*)d_ws + (size_t)BB * OFFC * HW * sizeof(float));

  offset_conv<<<BB * (H / 4), 256, 0, stream>>>(x, w_off, b_off, offs);
  sample_dw<<<BB * 16 * 4, 256, 0, stream>>>(x, offs, w_dw, dwbuf);
  pointwise<<<BB * 6 * 64, 256, 0, stream>>>(dwbuf, w_pw, out);
}

// Round 2
// 448.642 us; speedup vs baseline: 1.7006x; 1.7006x over previous
//
#include <hip/hip_runtime.h>

#define BB 16
#define C 192
#define COUT 384
#define H 64
#define W 64
#define HW (H * W)
#define KK 9
#define OFFC 18
#define PLW 68  // padded LDS plane row width: cols m=0 (logical -1), 1..64 (0..63), 65..67 zero

// ---------------------------------------------------------------------------
// Kernel A: offset conv (3x3, pad 1) -> offs[B][18][H][W]
// block = 1024 thr = 4 csplits x (4 rows x 64 cols); grid = B * 16 = 256
// weights read as wave-uniform scalar loads (SGPR operands); cross-split
// reduction through LDS. 16 waves/CU.
// ---------------------------------------------------------------------------
__global__ __launch_bounds__(1024) void offset_conv(
    const float* __restrict__ x, const float* __restrict__ w_off,
    const float* __restrict__ b_off, float* __restrict__ offs) {
  int blk = blockIdx.x;
  int b = blk >> 4;
  int h0 = (blk & 15) * 4;
  int tid = threadIdx.x;
  int csplit = tid >> 8;
  int sub = tid & 255;
  int r = sub >> 6;
  int w = sub & 63;
  int h = h0 + r;
  int cbase = csplit * 48;

  __shared__ float red[1024 * 6];  // 24 KB

  float acc[OFFC];
#pragma unroll
  for (int o = 0; o < OFFC; ++o) acc[o] = (csplit == 0) ? b_off[o] : 0.f;

  const float* xb = x + ((size_t)b * C + cbase) * HW;

  for (int cc = 0; cc < 48; ++cc) {
    const float* xc = xb + (size_t)cc * HW;
    float xv[KK];
#pragma unroll
    for (int di = 0; di < 3; ++di) {
      int yy = h + di - 1;
#pragma unroll
      for (int dj = 0; dj < 3; ++dj) {
        int xx = w + dj - 1;
        bool ok = (yy >= 0) && (yy < H) && (xx >= 0) && (xx < W);
        xv[di * 3 + dj] = ok ? xc[yy * W + xx] : 0.f;
      }
    }
#pragma unroll
    for (int o = 0; o < OFFC; ++o) {
      const float* wr = w_off + ((size_t)o * C + cbase + cc) * KK;  // uniform -> s_load
      float s = 0.f;
#pragma unroll
      for (int kk = 0; kk < KK; ++kk) s += xv[kk] * wr[kk];
      acc[o] += s;
    }
  }

  // cross-split reduction, 6 offset-channels per pass
  for (int c3 = 0; c3 < OFFC; c3 += 6) {
#pragma unroll
    for (int j = 0; j < 6; ++j) red[tid * 6 + j] = acc[c3 + j];
    __syncthreads();
    if (csplit == 0) {
#pragma unroll
      for (int j = 0; j < 6; ++j) {
        float s = red[(sub + 0) * 6 + j] + red[(sub + 256) * 6 + j] +
                  red[(sub + 512) * 6 + j] + red[(sub + 768) * 6 + j];
        offs[((size_t)b * OFFC + c3 + j) * HW + (size_t)h * W + w] = s;
      }
    }
    __syncthreads();
  }
}

// ---------------------------------------------------------------------------
// Kernel B: bilinear sample + depthwise -> dwout[B][C][H][W]
// block = 512 thr = 8 rows x 64 cols; 4-way channel split (48 ch each);
// grid = B * 8 * 4 = 512. Full padded channel plane staged in LDS (x2),
// gathers from LDS as adjacent-dword pairs (ds_read2), depthwise weights
// as scalar loads.
// ---------------------------------------------------------------------------
__global__ __launch_bounds__(512) void sample_dw(
    const float* __restrict__ x, const float* __restrict__ offs,
    const float* __restrict__ w_dw, float* __restrict__ dwout) {
  int blk = blockIdx.x;
  int csplit = blk & 3;
  int rowtile = (blk >> 2) & 7;
  int b = blk >> 5;
  int tid = threadIdx.x;
  int r = tid >> 6;
  int w = tid & 63;
  int h = rowtile * 8 + r;

  __shared__ float sbuf[2][H * PLW];  // 2 x 17408 B

  // zero padding columns once (persist across channels; staging only writes m=1..64)
  for (int i = tid; i < 2 * H * 4; i += 512) {
    int bf = i >> 8;
    int rr = (i >> 2) & 63;
    int p = i & 3;
    int m = (p == 0) ? 0 : (64 + p);  // m in {0,65,66,67}
    sbuf[bf][rr * PLW + m] = 0.f;
  }

  // per-pixel tap setup
  const float* ob = offs + (size_t)b * OFFC * HW + (size_t)h * W + w;
  int idx0[KK];
  int drow[KK];
  float wt[KK][4];
#pragma unroll
  for (int k = 0; k < KK; ++k) {
    int ki = k / 3, kj = k % 3;
    float oy = ob[(size_t)(2 * k) * HW];
    float ox = ob[(size_t)(2 * k + 1) * HW];
    float py = (float)(h - 1 + ki) + oy;
    float px = (float)(w - 1 + kj) + ox;
    float y0f = floorf(py), x0f = floorf(px);
    float dy = py - y0f, dx = px - x0f;
    int y0 = (int)y0f, x0 = (int)x0f;
    int y1 = y0 + 1, x1 = x0 + 1;
    float vy0 = (y0 >= 0 && y0 < H) ? 1.f : 0.f;
    float vy1 = (y1 >= 0 && y1 < H) ? 1.f : 0.f;
    float vx0 = (x0 >= 0 && x0 < W) ? 1.f : 0.f;
    float vx1 = (x1 >= 0 && x1 < W) ? 1.f : 0.f;
    int y0c = min(max(y0, 0), H - 1);
    int y1c = min(max(y1, 0), H - 1);
    int xm = min(max(x0, -1), 65) + 1;  // cols (xm-1, xm) logical; pads are zero
    idx0[k] = y0c * PLW + xm;
    drow[k] = (y1c - y0c) * PLW;
    wt[k][0] = (1.f - dy) * (1.f - dx) * vy0 * vx0;
    wt[k][1] = (1.f - dy) * dx * vy0 * vx1;
    wt[k][2] = dy * (1.f - dx) * vy1 * vx0;
    wt[k][3] = dy * dx * vy1 * vx1;
  }

  const int c0 = csplit * 48;
  const float* xsrc = x + ((size_t)b * C + c0) * HW;
  float* db = dwout + ((size_t)b * C + c0) * HW + (size_t)h * W + w;

  for (int cs = 0; cs < 48; cs += 2) {
    // stage 2 channel planes (interior cols only), fully coalesced
    const float* xp = xsrc + (size_t)cs * HW;
    for (int i = tid; i < 2 * HW; i += 512) {
      int ch = i >> 12;
      int p = i & 4095;
      int row = p >> 6;
      int col = p & 63;
      sbuf[ch][row * PLW + 1 + col] = xp[i];
    }
    __syncthreads();

#pragma unroll
    for (int ci = 0; ci < 2; ++ci) {
      const float* S = sbuf[ci];
      const float* wd = w_dw + (size_t)(c0 + cs + ci) * KK;  // uniform -> s_load
      float acc = 0.f;
#pragma unroll
      for (int k = 0; k < KK; ++k) {
        int i0 = idx0[k];
        int i1 = i0 + drow[k];
        float a0 = S[i0], a1 = S[i0 + 1];
        float a2 = S[i1], a3 = S[i1 + 1];
        float tap = fmaf(wt[k][3], a3,
                    fmaf(wt[k][2], a2, fmaf(wt[k][1], a1, wt[k][0] * a0)));
        acc = fmaf(wd[k], tap, acc);
      }
      db[(size_t)(cs + ci) * HW] = acc;
    }
    __syncthreads();
  }
}

// ---------------------------------------------------------------------------
// Kernel C: pointwise 1x1 conv as tiled GEMM: out[b][o][p] = sum_c dw*w_pw
// M=384 (o), N=4096 (p), K=192 (c) per batch. 64x64x16 tiles, 256 thr, 4x4.
// grid = B * 6 * 64 = 6144
// ---------------------------------------------------------------------------
__global__ __launch_bounds__(256) void pointwise(
    const float* __restrict__ dw, const float* __restrict__ w_pw,
    float* __restrict__ out) {
  int blk = blockIdx.x;
  int ntile = blk & 63;
  int mtile = (blk >> 6) % 6;
  int b = blk / (6 * 64);
  int n0 = ntile * 64;
  int m0 = mtile * 64;
  int tid = threadIdx.x;
  int tx = tid & 15, ty = tid >> 4;

  __shared__ float As[16][64];
  __shared__ float Bs[16][64];

  const float* dwb = dw + (size_t)b * C * HW;
  float acc[4][4] = {};

  for (int k0 = 0; k0 < C; k0 += 16) {
    __syncthreads();
    {
      int i = tid * 4;
      int m = i >> 4;
      int kk = i & 15;
      float4 v = *(const float4*)(w_pw + (size_t)(m0 + m) * C + k0 + kk);
      As[kk + 0][m] = v.x;
      As[kk + 1][m] = v.y;
      As[kk + 2][m] = v.z;
      As[kk + 3][m] = v.w;
      int kk2 = tid >> 4;
      int n = (tid & 15) * 4;
      float4 u = *(const float4*)(dwb + (size_t)(k0 + kk2) * HW + n0 + n);
      *(float4*)&Bs[kk2][n] = u;
    }
    __syncthreads();
#pragma unroll
    for (int kk = 0; kk < 16; ++kk) {
      float a[4], bb[4];
#pragma unroll
      for (int j = 0; j < 4; ++j) a[j] = As[kk][ty * 4 + j];
#pragma unroll
      for (int j = 0; j < 4; ++j) bb[j] = Bs[kk][tx * 4 + j];
#pragma unroll
      for (int i2 = 0; i2 < 4; ++i2)
#pragma unroll
        for (int j2 = 0; j2 < 4; ++j2) acc[i2][j2] += a[i2] * bb[j2];
    }
  }
  float* obp = out + ((size_t)b * COUT + m0 + ty * 4) * HW + n0 + tx * 4;
#pragma unroll
  for (int i2 = 0; i2 < 4; ++i2)
    *(float4*)(obp + (size_t)i2 * HW) =
        make_float4(acc[i2][0], acc[i2][1], acc[i2][2], acc[i2][3]);
}

// ---------------------------------------------------------------------------
extern "C" void kernel_launch(void* const* d_in, const int* in_sizes, int n_in,
                              void* d_out, int out_size, void* d_ws,
                              size_t ws_size, hipStream_t stream) {
  const float* x = (const float*)d_in[0];
  const float* w_off = (const float*)d_in[1];
  const float* b_off = (const float*)d_in[2];
  const float* w_dw = (const float*)d_in[3];
  const float* w_pw = (const float*)d_in[4];
  float* out = (float*)d_out;

  float* offs = (float*)d_ws;  // 16*18*4096 f32 = 4.7 MB
  float* dwbuf = (float*)((char*)d_ws + (size_t)BB * OFFC * HW * sizeof(float));

  offset_conv<<<BB * 16, 1024, 0, stream>>>(x, w_off, b_off, offs);
  sample_dw<<<BB * 8 * 4, 512, 0, stream>>>(x, offs, w_dw, dwbuf);
  pointwise<<<BB * 6 * 64, 256, 0, stream>>>(dwbuf, w_pw, out);
}

// Round 3
// 425.687 us; speedup vs baseline: 1.7923x; 1.0539x over previous
//
#include <hip/hip_runtime.h>

#define BB 16
#define C 192
#define COUT 384
#define H 64
#define W 64
#define HW (H * W)
#define KK 9
#define OFFC 18
#define PLW 68  // padded LDS plane row width
#define NCH 4   // channels staged per chunk in offset_conv

// ---------------------------------------------------------------------------
// Kernel A: offset conv (3x3, pad 1) -> offs[B][18][H][W]  (atomic partial sums)
// grid = B * 8 rowtiles * 4 csplits = 512 blocks, 256 thr, 2 px/thread.
// x planes + weights staged in LDS; weights padded to 12 floats for b128 reads.
// ---------------------------------------------------------------------------
__global__ __launch_bounds__(256) void offset_conv(
    const float* __restrict__ x, const float* __restrict__ w_off,
    const float* __restrict__ b_off, float* __restrict__ offs) {
  int blk = blockIdx.x;
  int csplit = blk & 3;
  int rowtile = (blk >> 2) & 7;
  int b = blk >> 5;
  int h0 = rowtile * 8;
  int tid = threadIdx.x;
  int r = tid >> 5;        // 0..7
  int cpair = tid & 31;    // 0..31
  int w0 = cpair * 2;
  int h = h0 + r;
  int cbase = csplit * 48;

  __shared__ __align__(16) float sx[NCH][10][PLW];  // 10880 B
  __shared__ __align__(16) float sw[NCH][OFFC][12]; // 3456 B

  float acc[OFFC][2];
#pragma unroll
  for (int o = 0; o < OFFC; ++o) {
    float bi = (csplit == 0) ? b_off[o] : 0.f;
    acc[o][0] = bi;
    acc[o][1] = bi;
  }

  const float* xb = x + ((size_t)b * C + cbase) * HW;

  for (int c0 = 0; c0 < 48; c0 += NCH) {
    __syncthreads();
    // stage x planes: logical rows h0-1 .. h0+8, logical cols -1..64 (+pad)
    for (int i = tid; i < NCH * 10 * PLW; i += 256) {
      int ch = i / (10 * PLW);
      int rem = i % (10 * PLW);
      int sr = rem / PLW;
      int m = rem % PLW;
      int ly = h0 + sr - 1;
      int lx = m - 1;
      float v = 0.f;
      if (ly >= 0 && ly < H && lx >= 0 && lx < W)
        v = xb[(size_t)(c0 + ch) * HW + ly * W + lx];
      sx[ch][sr][m] = v;
    }
    // stage weights
    for (int i = tid; i < NCH * OFFC * KK; i += 256) {
      int ch = i / (OFFC * KK);
      int rem = i % (OFFC * KK);
      int o = rem / KK;
      int k = rem % KK;
      sw[ch][o][k] = w_off[((size_t)o * C + cbase + c0 + ch) * KK + k];
    }
    __syncthreads();

#pragma unroll
    for (int cc = 0; cc < NCH; ++cc) {
      float xv[3][4];
#pragma unroll
      for (int dr = 0; dr < 3; ++dr) {
        float2 u0 = *(const float2*)&sx[cc][r + dr][w0];
        float2 u1 = *(const float2*)&sx[cc][r + dr][w0 + 2];
        xv[dr][0] = u0.x;
        xv[dr][1] = u0.y;
        xv[dr][2] = u1.x;
        xv[dr][3] = u1.y;
      }
#pragma unroll
      for (int o = 0; o < OFFC; ++o) {
        float4 wa = *(const float4*)&sw[cc][o][0];
        float4 wb = *(const float4*)&sw[cc][o][4];
        float w8 = sw[cc][o][8];
        acc[o][0] += wa.x * xv[0][0] + wa.y * xv[0][1] + wa.z * xv[0][2] +
                     wa.w * xv[1][0] + wb.x * xv[1][1] + wb.y * xv[1][2] +
                     wb.z * xv[2][0] + wb.w * xv[2][1] + w8 * xv[2][2];
        acc[o][1] += wa.x * xv[0][1] + wa.y * xv[0][2] + wa.z * xv[0][3] +
                     wa.w * xv[1][1] + wb.x * xv[1][2] + wb.y * xv[1][3] +
                     wb.z * xv[2][1] + wb.w * xv[2][2] + w8 * xv[2][3];
      }
    }
  }

  size_t base = (size_t)b * OFFC * HW + (size_t)h * W + w0;
#pragma unroll
  for (int o = 0; o < OFFC; ++o) {
    atomicAdd(&offs[base + (size_t)o * HW], acc[o][0]);
    atomicAdd(&offs[base + (size_t)o * HW + 1], acc[o][1]);
  }
}

// ---------------------------------------------------------------------------
// Kernel B: bilinear sample + depthwise -> dwout[B][C][H][W]
// (unchanged from round 2: LDS plane staging, ds_read2 taps)
// ---------------------------------------------------------------------------
__global__ __launch_bounds__(512) void sample_dw(
    const float* __restrict__ x, const float* __restrict__ offs,
    const float* __restrict__ w_dw, float* __restrict__ dwout) {
  int blk = blockIdx.x;
  int csplit = blk & 3;
  int rowtile = (blk >> 2) & 7;
  int b = blk >> 5;
  int tid = threadIdx.x;
  int r = tid >> 6;
  int w = tid & 63;
  int h = rowtile * 8 + r;

  __shared__ float sbuf[2][H * PLW];

  for (int i = tid; i < 2 * H * 4; i += 512) {
    int bf = i >> 8;
    int rr = (i >> 2) & 63;
    int p = i & 3;
    int m = (p == 0) ? 0 : (64 + p);
    sbuf[bf][rr * PLW + m] = 0.f;
  }

  const float* ob = offs + (size_t)b * OFFC * HW + (size_t)h * W + w;
  int idx0[KK];
  int drow[KK];
  float wt[KK][4];
#pragma unroll
  for (int k = 0; k < KK; ++k) {
    int ki = k / 3, kj = k % 3;
    float oy = ob[(size_t)(2 * k) * HW];
    float ox = ob[(size_t)(2 * k + 1) * HW];
    float py = (float)(h - 1 + ki) + oy;
    float px = (float)(w - 1 + kj) + ox;
    float y0f = floorf(py), x0f = floorf(px);
    float dy = py - y0f, dx = px - x0f;
    int y0 = (int)y0f, x0 = (int)x0f;
    int y1 = y0 + 1, x1 = x0 + 1;
    float vy0 = (y0 >= 0 && y0 < H) ? 1.f : 0.f;
    float vy1 = (y1 >= 0 && y1 < H) ? 1.f : 0.f;
    float vx0 = (x0 >= 0 && x0 < W) ? 1.f : 0.f;
    float vx1 = (x1 >= 0 && x1 < W) ? 1.f : 0.f;
    int y0c = min(max(y0, 0), H - 1);
    int y1c = min(max(y1, 0), H - 1);
    int xm = min(max(x0, -1), 65) + 1;
    idx0[k] = y0c * PLW + xm;
    drow[k] = (y1c - y0c) * PLW;
    wt[k][0] = (1.f - dy) * (1.f - dx) * vy0 * vx0;
    wt[k][1] = (1.f - dy) * dx * vy0 * vx1;
    wt[k][2] = dy * (1.f - dx) * vy1 * vx0;
    wt[k][3] = dy * dx * vy1 * vx1;
  }

  const int c0 = csplit * 48;
  const float* xsrc = x + ((size_t)b * C + c0) * HW;
  float* db = dwout + ((size_t)b * C + c0) * HW + (size_t)h * W + w;

  for (int cs = 0; cs < 48; cs += 2) {
    const float* xp = xsrc + (size_t)cs * HW;
    for (int i = tid; i < 2 * HW; i += 512) {
      int ch = i >> 12;
      int p = i & 4095;
      int row = p >> 6;
      int col = p & 63;
      sbuf[ch][row * PLW + 1 + col] = xp[i];
    }
    __syncthreads();

#pragma unroll
    for (int ci = 0; ci < 2; ++ci) {
      const float* S = sbuf[ci];
      const float* wd = w_dw + (size_t)(c0 + cs + ci) * KK;
      float acc = 0.f;
#pragma unroll
      for (int k = 0; k < KK; ++k) {
        int i0 = idx0[k];
        int i1 = i0 + drow[k];
        float a0 = S[i0], a1 = S[i0 + 1];
        float a2 = S[i1], a3 = S[i1 + 1];
        float tap = fmaf(wt[k][3], a3,
                    fmaf(wt[k][2], a2, fmaf(wt[k][1], a1, wt[k][0] * a0)));
        acc = fmaf(wd[k], tap, acc);
      }
      db[(size_t)(cs + ci) * HW] = acc;
    }
    __syncthreads();
  }
}

// ---------------------------------------------------------------------------
// Kernel C: pointwise 1x1 conv (fp32 tiled GEMM, unchanged)
// ---------------------------------------------------------------------------
__global__ __launch_bounds__(256) void pointwise(
    const float* __restrict__ dw, const float* __restrict__ w_pw,
    float* __restrict__ out) {
  int blk = blockIdx.x;
  int ntile = blk & 63;
  int mtile = (blk >> 6) % 6;
  int b = blk / (6 * 64);
  int n0 = ntile * 64;
  int m0 = mtile * 64;
  int tid = threadIdx.x;
  int tx = tid & 15, ty = tid >> 4;

  __shared__ float As[16][64];
  __shared__ float Bs[16][64];

  const float* dwb = dw + (size_t)b * C * HW;
  float acc[4][4] = {};

  for (int k0 = 0; k0 < C; k0 += 16) {
    __syncthreads();
    {
      int i = tid * 4;
      int m = i >> 4;
      int kk = i & 15;
      float4 v = *(const float4*)(w_pw + (size_t)(m0 + m) * C + k0 + kk);
      As[kk + 0][m] = v.x;
      As[kk + 1][m] = v.y;
      As[kk + 2][m] = v.z;
      As[kk + 3][m] = v.w;
      int kk2 = tid >> 4;
      int n = (tid & 15) * 4;
      float4 u = *(const float4*)(dwb + (size_t)(k0 + kk2) * HW + n0 + n);
      *(float4*)&Bs[kk2][n] = u;
    }
    __syncthreads();
#pragma unroll
    for (int kk = 0; kk < 16; ++kk) {
      float a[4], bb[4];
#pragma unroll
      for (int j = 0; j < 4; ++j) a[j] = As[kk][ty * 4 + j];
#pragma unroll
      for (int j = 0; j < 4; ++j) bb[j] = Bs[kk][tx * 4 + j];
#pragma unroll
      for (int i2 = 0; i2 < 4; ++i2)
#pragma unroll
        for (int j2 = 0; j2 < 4; ++j2) acc[i2][j2] += a[i2] * bb[j2];
    }
  }
  float* obp = out + ((size_t)b * COUT + m0 + ty * 4) * HW + n0 + tx * 4;
#pragma unroll
  for (int i2 = 0; i2 < 4; ++i2)
    *(float4*)(obp + (size_t)i2 * HW) =
        make_float4(acc[i2][0], acc[i2][1], acc[i2][2], acc[i2][3]);
}

// ---------------------------------------------------------------------------
extern "C" void kernel_launch(void* const* d_in, const int* in_sizes, int n_in,
                              void* d_out, int out_size, void* d_ws,
                              size_t ws_size, hipStream_t stream) {
  const float* x = (const float*)d_in[0];
  const float* w_off = (const float*)d_in[1];
  const float* b_off = (const float*)d_in[2];
  const float* w_dw = (const float*)d_in[3];
  const float* w_pw = (const float*)d_in[4];
  float* out = (float*)d_out;

  float* offs = (float*)d_ws;  // 16*18*4096 f32 = 4.7 MB
  float* dwbuf = (float*)((char*)d_ws + (size_t)BB * OFFC * HW * sizeof(float));

  hipMemsetAsync(offs, 0, (size_t)BB * OFFC * HW * sizeof(float), stream);
  offset_conv<<<BB * 8 * 4, 256, 0, stream>>>(x, w_off, b_off, offs);
  sample_dw<<<BB * 8 * 4, 512, 0, stream>>>(x, offs, w_dw, dwbuf);
  pointwise<<<BB * 6 * 64, 256, 0, stream>>>(dwbuf, w_pw, out);
}

// Round 4
// 279.707 us; speedup vs baseline: 2.7277x; 1.5219x over previous
//
#include <hip/hip_runtime.h>

#define BB 16
#define C 192
#define COUT 384
#define H 64
#define W 64
#define HW (H * W)
#define KK 9
#define OFFC 18
#define PLW 68

typedef __attribute__((ext_vector_type(8))) short short8;
typedef __attribute__((ext_vector_type(4))) float f32x4;

// round-to-nearest-even f32 -> bf16 bits
static __device__ inline unsigned short f2bf(float f) {
  union { float f; unsigned u; } v;
  v.f = f;
  unsigned r = v.u + 0x7FFF + ((v.u >> 16) & 1);
  return (unsigned short)(r >> 16);
}

// ---------------------------------------------------------------------------
// Prep: wA[k][o(32, zero-padded)][c(192)] bf16 from w_off[o][c][k] f32
// ---------------------------------------------------------------------------
__global__ __launch_bounds__(256) void prep_woff(
    const float* __restrict__ w_off, unsigned short* __restrict__ wA) {
  int idx = blockIdx.x * 256 + threadIdx.x;
  if (idx >= 9 * 32 * C) return;
  int k = idx / (32 * C);
  int rem = idx % (32 * C);
  int o = rem / C;
  int c = rem % C;
  float v = (o < OFFC) ? w_off[((size_t)o * C + c) * KK + k] : 0.f;
  wA[idx] = f2bf(v);
}

// ---------------------------------------------------------------------------
// Kernel A: offset conv via bf16 MFMA (9 shifted GEMMs over c)
// grid = B * 16 stripes (4 rows each) = 256 blocks, 256 thr = 4 waves.
// Wave wv computes output row h0+wv, all 64 cols (4 N-tiles of 16 px),
// M = 32 (18 real o, 2 M-tiles), K-loop = 6 chunks of 32 channels x 9 shifts.
// LDS: wlds[9][32][40] bf16 (per-chunk W slice), xlds[6 rows][68 cols][40] bf16.
// ---------------------------------------------------------------------------
__global__ __launch_bounds__(256) void offset_mfma(
    const float* __restrict__ x, const unsigned short* __restrict__ wA,
    const float* __restrict__ b_off, float* __restrict__ offs) {
  int blk = blockIdx.x;
  int b = blk >> 4;
  int h0 = (blk & 15) * 4;
  int tid = threadIdx.x;
  int lane = tid & 63;
  int wv = tid >> 6;    // wave id = output row r (0..3)
  int lpx = lane & 15;  // px / o-row within tile
  int lkg = lane >> 4;  // K-group (0..3)

  __shared__ __align__(16) unsigned short wlds[9 * 32 * 40];  // 23040 B
  __shared__ __align__(16) unsigned short xlds[6 * 68 * 40];  // 32640 B

  // zero the padding pixel-columns m=0 (col -1) and m=65 (col 64), once
  for (int i = tid; i < 6 * 2 * 16; i += 256) {
    int rr = i >> 5;
    int side = (i >> 4) & 1;
    int cd = i & 15;
    int m = side ? 65 : 0;
    ((unsigned*)xlds)[(rr * 68 + m) * 20 + cd] = 0u;
  }

  f32x4 acc[4][2];
#pragma unroll
  for (int nt = 0; nt < 4; ++nt)
#pragma unroll
    for (int m = 0; m < 2; ++m) acc[nt][m] = (f32x4){0.f, 0.f, 0.f, 0.f};

  const float* xb = x + (size_t)b * C * HW;

  for (int chunk = 0; chunk < 6; ++chunk) {
    int c0 = chunk * 32;
    __syncthreads();
    // stage weight slice: wlds[k*32+o][c 0..31] <- wA[(k*32+o)*192 + c0 + c]
#pragma unroll
    for (int t = 0; t < 18; ++t) {
      int i = t * 256 + tid;  // 4608 dwords
      int ko = i >> 4;
      int cd = i & 15;
      ((unsigned*)wlds)[ko * 20 + cd] =
          ((const unsigned*)wA)[ko * 96 + (c0 >> 1) + cd];
    }
    // stage x tile: rows h0-1..h0+4, cols 0..63 -> m=1..64, 32 channels (16 pairs)
#pragma unroll
    for (int t = 0; t < 24; ++t) {
      int i = t * 256 + tid;  // 6144 = 16 pairs * 6 rows * 64 cols
      int cc2 = i / 384;
      int rem = i % 384;
      int rr = rem >> 6;
      int col = rem & 63;
      int ly = h0 + rr - 1;
      float a0 = 0.f, a1 = 0.f;
      if (ly >= 0 && ly < H) {
        const float* xp = xb + (size_t)(c0 + 2 * cc2) * HW + ly * W + col;
        a0 = xp[0];
        a1 = xp[HW];
      }
      unsigned pack = ((unsigned)f2bf(a1) << 16) | (unsigned)f2bf(a0);
      ((unsigned*)xlds)[(rr * 68 + col + 1) * 20 + cc2] = pack;
    }
    __syncthreads();

    // A fragments: o = lpx (+16 for m-tile 1), k-slice = lkg*8..+7
    short8 af[9][2];
#pragma unroll
    for (int k = 0; k < 9; ++k)
#pragma unroll
      for (int m = 0; m < 2; ++m)
        af[k][m] = *(const short8*)&wlds[(k * 32 + m * 16 + lpx) * 40 + lkg * 8];

#pragma unroll
    for (int nt = 0; nt < 4; ++nt) {
#pragma unroll
      for (int k = 0; k < 9; ++k) {
        int ki = k / 3, kj = k % 3;
        short8 bf =
            *(const short8*)&xlds[((wv + ki) * 68 + nt * 16 + lpx + kj) * 40 +
                                  lkg * 8];
        acc[nt][0] = __builtin_amdgcn_mfma_f32_16x16x32_bf16(af[k][0], bf,
                                                             acc[nt][0], 0, 0, 0);
        acc[nt][1] = __builtin_amdgcn_mfma_f32_16x16x32_bf16(af[k][1], bf,
                                                             acc[nt][1], 0, 0, 0);
      }
    }
  }

  // store: D row = o = lkg*4 + j (+16), col px = nt*16 + lpx
  int h = h0 + wv;
#pragma unroll
  for (int nt = 0; nt < 4; ++nt) {
    int col = nt * 16 + lpx;
#pragma unroll
    for (int j = 0; j < 4; ++j) {
      int o = lkg * 4 + j;
      offs[((size_t)b * OFFC + o) * HW + h * W + col] = acc[nt][0][j] + b_off[o];
    }
    if (lkg == 0) {
#pragma unroll
      for (int j = 0; j < 2; ++j) {
        int o2 = 16 + j;
        offs[((size_t)b * OFFC + o2) * HW + h * W + col] =
            acc[nt][1][j] + b_off[o2];
      }
    }
  }
}

// ---------------------------------------------------------------------------
// Kernel B: bilinear sample + depthwise -> dwout[B][C][H][W]  (unchanged)
// ---------------------------------------------------------------------------
__global__ __launch_bounds__(512) void sample_dw(
    const float* __restrict__ x, const float* __restrict__ offs,
    const float* __restrict__ w_dw, float* __restrict__ dwout) {
  int blk = blockIdx.x;
  int csplit = blk & 3;
  int rowtile = (blk >> 2) & 7;
  int b = blk >> 5;
  int tid = threadIdx.x;
  int r = tid >> 6;
  int w = tid & 63;
  int h = rowtile * 8 + r;

  __shared__ float sbuf[2][H * PLW];

  for (int i = tid; i < 2 * H * 4; i += 512) {
    int bf = i >> 8;
    int rr = (i >> 2) & 63;
    int p = i & 3;
    int m = (p == 0) ? 0 : (64 + p);
    sbuf[bf][rr * PLW + m] = 0.f;
  }

  const float* ob = offs + (size_t)b * OFFC * HW + (size_t)h * W + w;
  int idx0[KK];
  int drow[KK];
  float wt[KK][4];
#pragma unroll
  for (int k = 0; k < KK; ++k) {
    int ki = k / 3, kj = k % 3;
    float oy = ob[(size_t)(2 * k) * HW];
    float ox = ob[(size_t)(2 * k + 1) * HW];
    float py = (float)(h - 1 + ki) + oy;
    float px = (float)(w - 1 + kj) + ox;
    float y0f = floorf(py), x0f = floorf(px);
    float dy = py - y0f, dx = px - x0f;
    int y0 = (int)y0f, x0 = (int)x0f;
    int y1 = y0 + 1, x1 = x0 + 1;
    float vy0 = (y0 >= 0 && y0 < H) ? 1.f : 0.f;
    float vy1 = (y1 >= 0 && y1 < H) ? 1.f : 0.f;
    float vx0 = (x0 >= 0 && x0 < W) ? 1.f : 0.f;
    float vx1 = (x1 >= 0 && x1 < W) ? 1.f : 0.f;
    int y0c = min(max(y0, 0), H - 1);
    int y1c = min(max(y1, 0), H - 1);
    int xm = min(max(x0, -1), 65) + 1;
    idx0[k] = y0c * PLW + xm;
    drow[k] = (y1c - y0c) * PLW;
    wt[k][0] = (1.f - dy) * (1.f - dx) * vy0 * vx0;
    wt[k][1] = (1.f - dy) * dx * vy0 * vx1;
    wt[k][2] = dy * (1.f - dx) * vy1 * vx0;
    wt[k][3] = dy * dx * vy1 * vx1;
  }

  const int c0 = csplit * 48;
  const float* xsrc = x + ((size_t)b * C + c0) * HW;
  float* db = dwout + ((size_t)b * C + c0) * HW + (size_t)h * W + w;

  for (int cs = 0; cs < 48; cs += 2) {
    const float* xp = xsrc + (size_t)cs * HW;
    for (int i = tid; i < 2 * HW; i += 512) {
      int ch = i >> 12;
      int p = i & 4095;
      int row = p >> 6;
      int col = p & 63;
      sbuf[ch][row * PLW + 1 + col] = xp[i];
    }
    __syncthreads();

#pragma unroll
    for (int ci = 0; ci < 2; ++ci) {
      const float* S = sbuf[ci];
      const float* wd = w_dw + (size_t)(c0 + cs + ci) * KK;
      float acc = 0.f;
#pragma unroll
      for (int k = 0; k < KK; ++k) {
        int i0 = idx0[k];
        int i1 = i0 + drow[k];
        float a0 = S[i0], a1 = S[i0 + 1];
        float a2 = S[i1], a3 = S[i1 + 1];
        float tap = fmaf(wt[k][3], a3,
                    fmaf(wt[k][2], a2, fmaf(wt[k][1], a1, wt[k][0] * a0)));
        acc = fmaf(wd[k], tap, acc);
      }
      db[(size_t)(cs + ci) * HW] = acc;
    }
    __syncthreads();
  }
}

// ---------------------------------------------------------------------------
// Kernel C: pointwise 1x1 conv (fp32 tiled GEMM, unchanged)
// ---------------------------------------------------------------------------
__global__ __launch_bounds__(256) void pointwise(
    const float* __restrict__ dw, const float* __restrict__ w_pw,
    float* __restrict__ out) {
  int blk = blockIdx.x;
  int ntile = blk & 63;
  int mtile = (blk >> 6) % 6;
  int b = blk / (6 * 64);
  int n0 = ntile * 64;
  int m0 = mtile * 64;
  int tid = threadIdx.x;
  int tx = tid & 15, ty = tid >> 4;

  __shared__ float As[16][64];
  __shared__ float Bs[16][64];

  const float* dwb = dw + (size_t)b * C * HW;
  float acc[4][4] = {};

  for (int k0 = 0; k0 < C; k0 += 16) {
    __syncthreads();
    {
      int i = tid * 4;
      int m = i >> 4;
      int kk = i & 15;
      float4 v = *(const float4*)(w_pw + (size_t)(m0 + m) * C + k0 + kk);
      As[kk + 0][m] = v.x;
      As[kk + 1][m] = v.y;
      As[kk + 2][m] = v.z;
      As[kk + 3][m] = v.w;
      int kk2 = tid >> 4;
      int n = (tid & 15) * 4;
      float4 u = *(const float4*)(dwb + (size_t)(k0 + kk2) * HW + n0 + n);
      *(float4*)&Bs[kk2][n] = u;
    }
    __syncthreads();
#pragma unroll
    for (int kk = 0; kk < 16; ++kk) {
      float a[4], bb[4];
#pragma unroll
      for (int j = 0; j < 4; ++j) a[j] = As[kk][ty * 4 + j];
#pragma unroll
      for (int j = 0; j < 4; ++j) bb[j] = Bs[kk][tx * 4 + j];
#pragma unroll
      for (int i2 = 0; i2 < 4; ++i2)
#pragma unroll
        for (int j2 = 0; j2 < 4; ++j2) acc[i2][j2] += a[i2] * bb[j2];
    }
  }
  float* obp = out + ((size_t)b * COUT + m0 + ty * 4) * HW + n0 + tx * 4;
#pragma unroll
  for (int i2 = 0; i2 < 4; ++i2)
    *(float4*)(obp + (size_t)i2 * HW) =
        make_float4(acc[i2][0], acc[i2][1], acc[i2][2], acc[i2][3]);
}

// ---------------------------------------------------------------------------
extern "C" void kernel_launch(void* const* d_in, const int* in_sizes, int n_in,
                              void* d_out, int out_size, void* d_ws,
                              size_t ws_size, hipStream_t stream) {
  const float* x = (const float*)d_in[0];
  const float* w_off = (const float*)d_in[1];
  const float* b_off = (const float*)d_in[2];
  const float* w_dw = (const float*)d_in[3];
  const float* w_pw = (const float*)d_in[4];
  float* out = (float*)d_out;

  float* offs = (float*)d_ws;  // 16*18*4096 f32 = 4.7 MB
  float* dwbuf = (float*)((char*)d_ws + (size_t)BB * OFFC * HW * sizeof(float));
  unsigned short* wA =
      (unsigned short*)((char*)d_ws +
                        ((size_t)BB * OFFC * HW + (size_t)BB * C * HW) *
                            sizeof(float));  // 9*32*192 bf16 = 110 KB

  prep_woff<<<(9 * 32 * C + 255) / 256, 256, 0, stream>>>(w_off, wA);
  offset_mfma<<<BB * 16, 256, 0, stream>>>(x, wA, b_off, offs);
  sample_dw<<<BB * 8 * 4, 512, 0, stream>>>(x, offs, w_dw, dwbuf);
  pointwise<<<BB * 6 * 64, 256, 0, stream>>>(dwbuf, w_pw, out);
}

// Round 5
// 234.354 us; speedup vs baseline: 3.2555x; 1.1935x over previous
//
#include <hip/hip_runtime.h>

#define BB 16
#define C 192
#define COUT 384
#define H 64
#define W 64
#define HW (H * W)
#define KK 9
#define OFFC 18
#define PLW 68

typedef __attribute__((ext_vector_type(8))) short short8;
typedef __attribute__((ext_vector_type(4))) float f32x4;

// round-to-nearest-even f32 -> bf16 bits
static __device__ inline unsigned short f2bf(float f) {
  union { float f; unsigned u; } v;
  v.f = f;
  unsigned r = v.u + 0x7FFF + ((v.u >> 16) & 1);
  return (unsigned short)(r >> 16);
}

static __device__ inline short8 ld_frag8(const unsigned* p) {
  union { unsigned u[4]; short8 s; } v;
  uint2 a = *(const uint2*)p;
  uint2 b = *(const uint2*)(p + 2);
  v.u[0] = a.x; v.u[1] = a.y; v.u[2] = b.x; v.u[3] = b.y;
  return v.s;
}

// ---------------------------------------------------------------------------
// Prep: wA[k][o(32, zero-padded)][c(192)] bf16 from w_off[o][c][k] f32
// ---------------------------------------------------------------------------
__global__ __launch_bounds__(256) void prep_woff(
    const float* __restrict__ w_off, unsigned short* __restrict__ wA) {
  int idx = blockIdx.x * 256 + threadIdx.x;
  if (idx >= 9 * 32 * C) return;
  int k = idx / (32 * C);
  int rem = idx % (32 * C);
  int o = rem / C;
  int c = rem % C;
  float v = (o < OFFC) ? w_off[((size_t)o * C + c) * KK + k] : 0.f;
  wA[idx] = f2bf(v);
}

// ---------------------------------------------------------------------------
// Prep: wPW[o][cd] packed bf16 c-pairs from w_pw[o][c] f32  (384 x 96 dwords)
// ---------------------------------------------------------------------------
__global__ __launch_bounds__(256) void prep_wpw(
    const float* __restrict__ w_pw, unsigned* __restrict__ wPW) {
  int idx = blockIdx.x * 256 + threadIdx.x;
  if (idx >= COUT * (C / 2)) return;
  float2 v = *(const float2*)(w_pw + (size_t)idx * 2);
  wPW[idx] = ((unsigned)f2bf(v.y) << 16) | (unsigned)f2bf(v.x);
}

// ---------------------------------------------------------------------------
// Kernel A: offset conv via bf16 MFMA (9 shifted GEMMs over c)  [unchanged]
// ---------------------------------------------------------------------------
__global__ __launch_bounds__(256) void offset_mfma(
    const float* __restrict__ x, const unsigned short* __restrict__ wA,
    const float* __restrict__ b_off, float* __restrict__ offs) {
  int blk = blockIdx.x;
  int b = blk >> 4;
  int h0 = (blk & 15) * 4;
  int tid = threadIdx.x;
  int lane = tid & 63;
  int wv = tid >> 6;
  int lpx = lane & 15;
  int lkg = lane >> 4;

  __shared__ __align__(16) unsigned short wlds[9 * 32 * 40];
  __shared__ __align__(16) unsigned short xlds[6 * 68 * 40];

  for (int i = tid; i < 6 * 2 * 16; i += 256) {
    int rr = i >> 5;
    int side = (i >> 4) & 1;
    int cd = i & 15;
    int m = side ? 65 : 0;
    ((unsigned*)xlds)[(rr * 68 + m) * 20 + cd] = 0u;
  }

  f32x4 acc[4][2];
#pragma unroll
  for (int nt = 0; nt < 4; ++nt)
#pragma unroll
    for (int m = 0; m < 2; ++m) acc[nt][m] = (f32x4){0.f, 0.f, 0.f, 0.f};

  const float* xb = x + (size_t)b * C * HW;

  for (int chunk = 0; chunk < 6; ++chunk) {
    int c0 = chunk * 32;
    __syncthreads();
#pragma unroll
    for (int t = 0; t < 18; ++t) {
      int i = t * 256 + tid;
      int ko = i >> 4;
      int cd = i & 15;
      ((unsigned*)wlds)[ko * 20 + cd] =
          ((const unsigned*)wA)[ko * 96 + (c0 >> 1) + cd];
    }
#pragma unroll
    for (int t = 0; t < 24; ++t) {
      int i = t * 256 + tid;
      int cc2 = i / 384;
      int rem = i % 384;
      int rr = rem >> 6;
      int col = rem & 63;
      int ly = h0 + rr - 1;
      float a0 = 0.f, a1 = 0.f;
      if (ly >= 0 && ly < H) {
        const float* xp = xb + (size_t)(c0 + 2 * cc2) * HW + ly * W + col;
        a0 = xp[0];
        a1 = xp[HW];
      }
      unsigned pack = ((unsigned)f2bf(a1) << 16) | (unsigned)f2bf(a0);
      ((unsigned*)xlds)[(rr * 68 + col + 1) * 20 + cc2] = pack;
    }
    __syncthreads();

    short8 af[9][2];
#pragma unroll
    for (int k = 0; k < 9; ++k)
#pragma unroll
      for (int m = 0; m < 2; ++m)
        af[k][m] = *(const short8*)&wlds[(k * 32 + m * 16 + lpx) * 40 + lkg * 8];

#pragma unroll
    for (int nt = 0; nt < 4; ++nt) {
#pragma unroll
      for (int k = 0; k < 9; ++k) {
        int ki = k / 3, kj = k % 3;
        short8 bf =
            *(const short8*)&xlds[((wv + ki) * 68 + nt * 16 + lpx + kj) * 40 +
                                  lkg * 8];
        acc[nt][0] = __builtin_amdgcn_mfma_f32_16x16x32_bf16(af[k][0], bf,
                                                             acc[nt][0], 0, 0, 0);
        acc[nt][1] = __builtin_amdgcn_mfma_f32_16x16x32_bf16(af[k][1], bf,
                                                             acc[nt][1], 0, 0, 0);
      }
    }
  }

  int h = h0 + wv;
#pragma unroll
  for (int nt = 0; nt < 4; ++nt) {
    int col = nt * 16 + lpx;
#pragma unroll
    for (int j = 0; j < 4; ++j) {
      int o = lkg * 4 + j;
      offs[((size_t)b * OFFC + o) * HW + h * W + col] = acc[nt][0][j] + b_off[o];
    }
    if (lkg == 0) {
#pragma unroll
      for (int j = 0; j < 2; ++j) {
        int o2 = 16 + j;
        offs[((size_t)b * OFFC + o2) * HW + h * W + col] =
            acc[nt][1][j] + b_off[o2];
      }
    }
  }
}

// ---------------------------------------------------------------------------
// Kernel B: bilinear sample + depthwise -> dwp[B][96][HW] packed bf16 c-pairs
// ---------------------------------------------------------------------------
__global__ __launch_bounds__(512) void sample_dw(
    const float* __restrict__ x, const float* __restrict__ offs,
    const float* __restrict__ w_dw, unsigned* __restrict__ dwp) {
  int blk = blockIdx.x;
  int csplit = blk & 3;
  int rowtile = (blk >> 2) & 7;
  int b = blk >> 5;
  int tid = threadIdx.x;
  int r = tid >> 6;
  int w = tid & 63;
  int h = rowtile * 8 + r;

  __shared__ float sbuf[2][H * PLW];

  for (int i = tid; i < 2 * H * 4; i += 512) {
    int bf = i >> 8;
    int rr = (i >> 2) & 63;
    int p = i & 3;
    int m = (p == 0) ? 0 : (64 + p);
    sbuf[bf][rr * PLW + m] = 0.f;
  }

  const float* ob = offs + (size_t)b * OFFC * HW + (size_t)h * W + w;
  int idx0[KK];
  int drow[KK];
  float wt[KK][4];
#pragma unroll
  for (int k = 0; k < KK; ++k) {
    int ki = k / 3, kj = k % 3;
    float oy = ob[(size_t)(2 * k) * HW];
    float ox = ob[(size_t)(2 * k + 1) * HW];
    float py = (float)(h - 1 + ki) + oy;
    float px = (float)(w - 1 + kj) + ox;
    float y0f = floorf(py), x0f = floorf(px);
    float dy = py - y0f, dx = px - x0f;
    int y0 = (int)y0f, x0 = (int)x0f;
    int y1 = y0 + 1, x1 = x0 + 1;
    float vy0 = (y0 >= 0 && y0 < H) ? 1.f : 0.f;
    float vy1 = (y1 >= 0 && y1 < H) ? 1.f : 0.f;
    float vx0 = (x0 >= 0 && x0 < W) ? 1.f : 0.f;
    float vx1 = (x1 >= 0 && x1 < W) ? 1.f : 0.f;
    int y0c = min(max(y0, 0), H - 1);
    int y1c = min(max(y1, 0), H - 1);
    int xm = min(max(x0, -1), 65) + 1;
    idx0[k] = y0c * PLW + xm;
    drow[k] = (y1c - y0c) * PLW;
    wt[k][0] = (1.f - dy) * (1.f - dx) * vy0 * vx0;
    wt[k][1] = (1.f - dy) * dx * vy0 * vx1;
    wt[k][2] = dy * (1.f - dx) * vy1 * vx0;
    wt[k][3] = dy * dx * vy1 * vx1;
  }

  const int c0 = csplit * 48;
  const float* xsrc = x + ((size_t)b * C + c0) * HW;

  for (int cs = 0; cs < 48; cs += 2) {
    const float* xp = xsrc + (size_t)cs * HW;
    for (int i = tid; i < 2 * HW; i += 512) {
      int ch = i >> 12;
      int p = i & 4095;
      int row = p >> 6;
      int col = p & 63;
      sbuf[ch][row * PLW + 1 + col] = xp[i];
    }
    __syncthreads();

    float accv[2];
#pragma unroll
    for (int ci = 0; ci < 2; ++ci) {
      const float* S = sbuf[ci];
      const float* wd = w_dw + (size_t)(c0 + cs + ci) * KK;
      float acc = 0.f;
#pragma unroll
      for (int k = 0; k < KK; ++k) {
        int i0 = idx0[k];
        int i1 = i0 + drow[k];
        float a0 = S[i0], a1 = S[i0 + 1];
        float a2 = S[i1], a3 = S[i1 + 1];
        float tap = fmaf(wt[k][3], a3,
                    fmaf(wt[k][2], a2, fmaf(wt[k][1], a1, wt[k][0] * a0)));
        acc = fmaf(wd[k], tap, acc);
      }
      accv[ci] = acc;
    }
    unsigned pack = ((unsigned)f2bf(accv[1]) << 16) | (unsigned)f2bf(accv[0]);
    dwp[((size_t)b * 96 + ((c0 + cs) >> 1)) * HW + (size_t)h * W + w] = pack;
    __syncthreads();
  }
}

// ---------------------------------------------------------------------------
// Kernel C: pointwise 1x1 conv via bf16 MFMA.
// GEMM per batch: out[o][p] = sum_c w_pw[o][c] * dw[p][c]
// block 256 thr = 4 waves (2M x 2N), tile BM=128, BN=64, K chunks of 32.
// grid = B * 3 Mtiles * 64 Ntiles = 3072.
// LDS rows 22 dwords (44 bf16): <=4-way write conflicts, clean b64 reads.
// ---------------------------------------------------------------------------
__global__ __launch_bounds__(256) void pointwise_mfma(
    const unsigned* __restrict__ dwp, const unsigned* __restrict__ wPW,
    float* __restrict__ out) {
  int blk = blockIdx.x;
  int nt = blk & 63;
  int mt = (blk >> 6) % 3;
  int b = blk / 192;
  int n0 = nt * 64;
  int m0 = mt * 128;
  int tid = threadIdx.x;
  int lane = tid & 63;
  int wv = tid >> 6;
  int wm = wv >> 1;
  int wn = wv & 1;
  int lpx = lane & 15;
  int lkg = lane >> 4;

  __shared__ __align__(16) unsigned sA[128 * 22];  // 11264 B
  __shared__ __align__(16) unsigned sB[64 * 22];   // 5632 B

  f32x4 acc[4][2];
#pragma unroll
  for (int mf = 0; mf < 4; ++mf)
#pragma unroll
    for (int nf = 0; nf < 2; ++nf) acc[mf][nf] = (f32x4){0.f, 0.f, 0.f, 0.f};

  const unsigned* dwb = dwp + (size_t)b * 96 * HW + n0;

  for (int chunk = 0; chunk < 6; ++chunk) {
    int kp0 = chunk * 16;
    __syncthreads();
#pragma unroll
    for (int t = 0; t < 8; ++t) {  // A: 128 rows x 16 dwords
      int i = t * 256 + tid;
      int m = i >> 4;
      int cd = i & 15;
      sA[m * 22 + cd] = wPW[(size_t)(m0 + m) * 96 + kp0 + cd];
    }
#pragma unroll
    for (int t = 0; t < 4; ++t) {  // B: 16 kpairs x 64 px
      int i = t * 256 + tid;
      int kp = i >> 6;
      int px = i & 63;
      sB[px * 22 + kp] = dwb[(size_t)(kp0 + kp) * HW + px];
    }
    __syncthreads();

    short8 af[4];
#pragma unroll
    for (int mf = 0; mf < 4; ++mf) {
      int m = wm * 64 + mf * 16 + lpx;
      af[mf] = ld_frag8(&sA[m * 22 + lkg * 4]);
    }
    short8 bf[2];
#pragma unroll
    for (int nf = 0; nf < 2; ++nf) {
      int px = wn * 32 + nf * 16 + lpx;
      bf[nf] = ld_frag8(&sB[px * 22 + lkg * 4]);
    }
#pragma unroll
    for (int mf = 0; mf < 4; ++mf)
#pragma unroll
      for (int nf = 0; nf < 2; ++nf)
        acc[mf][nf] = __builtin_amdgcn_mfma_f32_16x16x32_bf16(
            af[mf], bf[nf], acc[mf][nf], 0, 0, 0);
  }

#pragma unroll
  for (int mf = 0; mf < 4; ++mf) {
#pragma unroll
    for (int nf = 0; nf < 2; ++nf) {
      int px = n0 + wn * 32 + nf * 16 + lpx;
#pragma unroll
      for (int j = 0; j < 4; ++j) {
        int o = m0 + wm * 64 + mf * 16 + lkg * 4 + j;
        out[((size_t)b * COUT + o) * HW + px] = acc[mf][nf][j];
      }
    }
  }
}

// ---------------------------------------------------------------------------
extern "C" void kernel_launch(void* const* d_in, const int* in_sizes, int n_in,
                              void* d_out, int out_size, void* d_ws,
                              size_t ws_size, hipStream_t stream) {
  const float* x = (const float*)d_in[0];
  const float* w_off = (const float*)d_in[1];
  const float* b_off = (const float*)d_in[2];
  const float* w_dw = (const float*)d_in[3];
  const float* w_pw = (const float*)d_in[4];
  float* out = (float*)d_out;

  char* ws = (char*)d_ws;
  float* offs = (float*)ws;                       // 4.72 MB
  unsigned* dwp = (unsigned*)(ws + 4718592);      // 25.17 MB
  unsigned short* wA = (unsigned short*)(ws + 4718592 + 25165824);  // 110 KB
  unsigned* wPW = (unsigned*)(ws + 4718592 + 25165824 + 110592);    // 147 KB

  prep_woff<<<(9 * 32 * C + 255) / 256, 256, 0, stream>>>(w_off, wA);
  prep_wpw<<<(COUT * (C / 2) + 255) / 256, 256, 0, stream>>>(w_pw, wPW);
  offset_mfma<<<BB * 16, 256, 0, stream>>>(x, wA, b_off, offs);
  sample_dw<<<BB * 8 * 4, 512, 0, stream>>>(x, offs, w_dw, dwp);
  pointwise_mfma<<<BB * 3 * 64, 256, 0, stream>>>(dwp, wPW, out);
}

// Round 6
// 195.227 us; speedup vs baseline: 3.9080x; 1.2004x over previous
//
#include <hip/hip_runtime.h>

#define BB 16
#define C 192
#define COUT 384
#define H 64
#define W 64
#define HW (H * W)
#define KK 9
#define OFFC 18
#define WROWS 22  // sample_dw staged window rows: [h0-7, h0+15)

typedef __attribute__((ext_vector_type(8))) short short8;
typedef __attribute__((ext_vector_type(4))) float f32x4;

// round-to-nearest-even f32 -> bf16 bits
static __device__ inline unsigned short f2bf(float f) {
  union { float f; unsigned u; } v;
  v.f = f;
  unsigned r = v.u + 0x7FFF + ((v.u >> 16) & 1);
  return (unsigned short)(r >> 16);
}

static __device__ inline float blo(unsigned u) {
  union { unsigned u; float f; } v;
  v.u = u << 16;
  return v.f;
}
static __device__ inline float bhi(unsigned u) {
  union { unsigned u; float f; } v;
  v.u = u & 0xFFFF0000u;
  return v.f;
}

static __device__ inline short8 ld_frag8(const unsigned* p) {
  union { unsigned u[4]; short8 s; } v;
  uint2 a = *(const uint2*)p;
  uint2 b = *(const uint2*)(p + 2);
  v.u[0] = a.x; v.u[1] = a.y; v.u[2] = b.x; v.u[3] = b.y;
  return v.s;
}

// ---------------------------------------------------------------------------
// Prep: wA[k][o(32, zero-padded)][c(192)] bf16 from w_off[o][c][k] f32
// ---------------------------------------------------------------------------
__global__ __launch_bounds__(256) void prep_woff(
    const float* __restrict__ w_off, unsigned short* __restrict__ wA) {
  int idx = blockIdx.x * 256 + threadIdx.x;
  if (idx >= 9 * 32 * C) return;
  int k = idx / (32 * C);
  int rem = idx % (32 * C);
  int o = rem / C;
  int c = rem % C;
  float v = (o < OFFC) ? w_off[((size_t)o * C + c) * KK + k] : 0.f;
  wA[idx] = f2bf(v);
}

// ---------------------------------------------------------------------------
// Prep: wPW[o][cd] packed bf16 c-pairs from w_pw[o][c] f32  (384 x 96 dwords)
// ---------------------------------------------------------------------------
__global__ __launch_bounds__(256) void prep_wpw(
    const float* __restrict__ w_pw, unsigned* __restrict__ wPW) {
  int idx = blockIdx.x * 256 + threadIdx.x;
  if (idx >= COUT * (C / 2)) return;
  float2 v = *(const float2*)(w_pw + (size_t)idx * 2);
  wPW[idx] = ((unsigned)f2bf(v.y) << 16) | (unsigned)f2bf(v.x);
}

// ---------------------------------------------------------------------------
// Kernel A: offset conv via bf16 MFMA (9 shifted GEMMs over c)  [unchanged]
// ---------------------------------------------------------------------------
__global__ __launch_bounds__(256) void offset_mfma(
    const float* __restrict__ x, const unsigned short* __restrict__ wA,
    const float* __restrict__ b_off, float* __restrict__ offs) {
  int blk = blockIdx.x;
  int b = blk >> 4;
  int h0 = (blk & 15) * 4;
  int tid = threadIdx.x;
  int lane = tid & 63;
  int wv = tid >> 6;
  int lpx = lane & 15;
  int lkg = lane >> 4;

  __shared__ __align__(16) unsigned short wlds[9 * 32 * 40];
  __shared__ __align__(16) unsigned short xlds[6 * 68 * 40];

  for (int i = tid; i < 6 * 2 * 16; i += 256) {
    int rr = i >> 5;
    int side = (i >> 4) & 1;
    int cd = i & 15;
    int m = side ? 65 : 0;
    ((unsigned*)xlds)[(rr * 68 + m) * 20 + cd] = 0u;
  }

  f32x4 acc[4][2];
#pragma unroll
  for (int nt = 0; nt < 4; ++nt)
#pragma unroll
    for (int m = 0; m < 2; ++m) acc[nt][m] = (f32x4){0.f, 0.f, 0.f, 0.f};

  const float* xb = x + (size_t)b * C * HW;

  for (int chunk = 0; chunk < 6; ++chunk) {
    int c0 = chunk * 32;
    __syncthreads();
#pragma unroll
    for (int t = 0; t < 18; ++t) {
      int i = t * 256 + tid;
      int ko = i >> 4;
      int cd = i & 15;
      ((unsigned*)wlds)[ko * 20 + cd] =
          ((const unsigned*)wA)[ko * 96 + (c0 >> 1) + cd];
    }
#pragma unroll
    for (int t = 0; t < 24; ++t) {
      int i = t * 256 + tid;
      int cc2 = i / 384;
      int rem = i % 384;
      int rr = rem >> 6;
      int col = rem & 63;
      int ly = h0 + rr - 1;
      float a0 = 0.f, a1 = 0.f;
      if (ly >= 0 && ly < H) {
        const float* xp = xb + (size_t)(c0 + 2 * cc2) * HW + ly * W + col;
        a0 = xp[0];
        a1 = xp[HW];
      }
      unsigned pack = ((unsigned)f2bf(a1) << 16) | (unsigned)f2bf(a0);
      ((unsigned*)xlds)[(rr * 68 + col + 1) * 20 + cc2] = pack;
    }
    __syncthreads();

    short8 af[9][2];
#pragma unroll
    for (int k = 0; k < 9; ++k)
#pragma unroll
      for (int m = 0; m < 2; ++m)
        af[k][m] = *(const short8*)&wlds[(k * 32 + m * 16 + lpx) * 40 + lkg * 8];

#pragma unroll
    for (int nt = 0; nt < 4; ++nt) {
#pragma unroll
      for (int k = 0; k < 9; ++k) {
        int ki = k / 3, kj = k % 3;
        short8 bf =
            *(const short8*)&xlds[((wv + ki) * 68 + nt * 16 + lpx + kj) * 40 +
                                  lkg * 8];
        acc[nt][0] = __builtin_amdgcn_mfma_f32_16x16x32_bf16(af[k][0], bf,
                                                             acc[nt][0], 0, 0, 0);
        acc[nt][1] = __builtin_amdgcn_mfma_f32_16x16x32_bf16(af[k][1], bf,
                                                             acc[nt][1], 0, 0, 0);
      }
    }
  }

  int h = h0 + wv;
#pragma unroll
  for (int nt = 0; nt < 4; ++nt) {
    int col = nt * 16 + lpx;
#pragma unroll
    for (int j = 0; j < 4; ++j) {
      int o = lkg * 4 + j;
      offs[((size_t)b * OFFC + o) * HW + h * W + col] = acc[nt][0][j] + b_off[o];
    }
    if (lkg == 0) {
#pragma unroll
      for (int j = 0; j < 2; ++j) {
        int o2 = 16 + j;
        offs[((size_t)b * OFFC + o2) * HW + h * W + col] =
            acc[nt][1][j] + b_off[o2];
      }
    }
  }
}

// ---------------------------------------------------------------------------
// Kernel B: bilinear sample + depthwise -> dwp[B][96][HW] packed bf16 c-pairs
// block 512 thr = 8 rows x 64 cols; 8-way channel split (24 ch, 6 quads);
// grid = B * 8 rowtiles * 8 csplits = 1024.
// x staged as 22-row window, 4 channels packed per uint2 cell (bf16 x4);
// per tap: 2x ds_read2_b64 serves 4 channels. Out-of-window taps (|off|>~5,
// ~12 sigma) fall back to direct global gathers for full correctness.
// ---------------------------------------------------------------------------
__global__ __launch_bounds__(512) void sample_dw(
    const float* __restrict__ x, const float* __restrict__ offs,
    const float* __restrict__ w_dw, unsigned* __restrict__ dwp) {
  int blk = blockIdx.x;
  int csplit = blk & 7;
  int rowtile = (blk >> 3) & 7;
  int b = blk >> 6;
  int tid = threadIdx.x;
  int r = tid >> 6;
  int w = tid & 63;
  int h = rowtile * 8 + r;
  int lo = rowtile * 8 - 7;  // window rows [lo, lo+WROWS)

  __shared__ uint2 S[WROWS * 68];  // 11968 B

  // zero pad columns {0,65,66,67} once (staging writes cols 1..64 only)
  for (int i = tid; i < WROWS * 4; i += 512) {
    int rr = i >> 2;
    int p = i & 3;
    int m = (p == 0) ? 0 : 64 + p;
    S[rr * 68 + m] = make_uint2(0u, 0u);
  }

  // per-pixel tap setup (channel-independent)
  const float* ob = offs + (size_t)b * OFFC * HW + (size_t)h * W + w;
  int idxA[KK], idxB[KK], gpk[KK];
  float wt[KK][4];
  int okmask = 0;
#pragma unroll
  for (int k = 0; k < KK; ++k) {
    int ki = k / 3, kj = k % 3;
    float oy = ob[(size_t)(2 * k) * HW];
    float ox = ob[(size_t)(2 * k + 1) * HW];
    float py = (float)(h - 1 + ki) + oy;
    float px = (float)(w - 1 + kj) + ox;
    float y0f = floorf(py), x0f = floorf(px);
    float dy = py - y0f, dx = px - x0f;
    int y0 = (int)y0f, x0 = (int)x0f;
    int y1 = y0 + 1, x1 = x0 + 1;
    float vy0 = (y0 >= 0 && y0 < H) ? 1.f : 0.f;
    float vy1 = (y1 >= 0 && y1 < H) ? 1.f : 0.f;
    float vx0 = (x0 >= 0 && x0 < W) ? 1.f : 0.f;
    float vx1 = (x1 >= 0 && x1 < W) ? 1.f : 0.f;
    int y0c = min(max(y0, 0), H - 1);
    int y1c = min(max(y1, 0), H - 1);
    int xc0 = min(max(x0, 0), W - 1);
    int xc1 = min(max(x1, 0), W - 1);
    int xm = min(max(x0, -1), 65) + 1;  // plane cols (xm, xm+1)
    int wy0 = y0c - lo, wy1 = y1c - lo;
    bool ok = ((unsigned)wy0 < WROWS) && ((unsigned)wy1 < WROWS);
    okmask |= ((int)ok) << k;
    idxA[k] = wy0 * 68 + xm;
    idxB[k] = wy1 * 68 + xm;
    gpk[k] = y0c | (y1c << 6) | (xc0 << 12) | (xc1 << 18);
    wt[k][0] = (1.f - dy) * (1.f - dx) * vy0 * vx0;
    wt[k][1] = (1.f - dy) * dx * vy0 * vx1;
    wt[k][2] = dy * (1.f - dx) * vy1 * vx0;
    wt[k][3] = dy * dx * vy1 * vx1;
  }

  const int c0 = csplit * 24;
  const float* xq0 = x + ((size_t)b * C + c0) * HW;

  for (int q = 0; q < 6; ++q) {
    const float* xq = xq0 + (size_t)(q * 4) * HW;
    __syncthreads();
    // stage 4-channel packed window (coalesced)
    for (int i = tid; i < WROWS * 64; i += 512) {
      int rr = i >> 6;
      int col = i & 63;
      int ly = lo + rr;
      uint2 p = make_uint2(0u, 0u);
      if (ly >= 0 && ly < H) {
        const float* xp = xq + (size_t)ly * W + col;
        p.x = ((unsigned)f2bf(xp[HW]) << 16) | (unsigned)f2bf(xp[0]);
        p.y = ((unsigned)f2bf(xp[3 * HW]) << 16) | (unsigned)f2bf(xp[2 * HW]);
      }
      S[rr * 68 + col + 1] = p;
    }
    __syncthreads();

    int cq = c0 + q * 4;
    const float* wd = w_dw + (size_t)cq * KK;  // block-uniform -> s_load
    float acc0 = 0.f, acc1 = 0.f, acc2 = 0.f, acc3 = 0.f;
#pragma unroll
    for (int k = 0; k < KK; ++k) {
      float w0 = wt[k][0], w1 = wt[k][1], w2 = wt[k][2], w3 = wt[k][3];
      float t0, t1, t2, t3;
      if (__builtin_expect((okmask >> k) & 1, 1)) {
        uint2 u00 = S[idxA[k]], u01 = S[idxA[k] + 1];
        uint2 u10 = S[idxB[k]], u11 = S[idxB[k] + 1];
        t0 = fmaf(w3, blo(u11.x),
             fmaf(w2, blo(u10.x), fmaf(w1, blo(u01.x), w0 * blo(u00.x))));
        t1 = fmaf(w3, bhi(u11.x),
             fmaf(w2, bhi(u10.x), fmaf(w1, bhi(u01.x), w0 * bhi(u00.x))));
        t2 = fmaf(w3, blo(u11.y),
             fmaf(w2, blo(u10.y), fmaf(w1, blo(u01.y), w0 * blo(u00.y))));
        t3 = fmaf(w3, bhi(u11.y),
             fmaf(w2, bhi(u10.y), fmaf(w1, bhi(u01.y), w0 * bhi(u00.y))));
      } else {  // out-of-window fallback: direct global gather (f32)
        int g = gpk[k];
        int a00 = (g & 63) * W + ((g >> 12) & 63);
        int a01 = (g & 63) * W + ((g >> 18) & 63);
        int a10 = ((g >> 6) & 63) * W + ((g >> 12) & 63);
        int a11 = ((g >> 6) & 63) * W + ((g >> 18) & 63);
        const float* p0 = xq;
        const float* p1 = xq + HW;
        const float* p2 = xq + 2 * HW;
        const float* p3 = xq + 3 * HW;
        t0 = fmaf(w3, p0[a11], fmaf(w2, p0[a10], fmaf(w1, p0[a01], w0 * p0[a00])));
        t1 = fmaf(w3, p1[a11], fmaf(w2, p1[a10], fmaf(w1, p1[a01], w0 * p1[a00])));
        t2 = fmaf(w3, p2[a11], fmaf(w2, p2[a10], fmaf(w1, p2[a01], w0 * p2[a00])));
        t3 = fmaf(w3, p3[a11], fmaf(w2, p3[a10], fmaf(w1, p3[a01], w0 * p3[a00])));
      }
      acc0 = fmaf(wd[k], t0, acc0);
      acc1 = fmaf(wd[KK + k], t1, acc1);
      acc2 = fmaf(wd[2 * KK + k], t2, acc2);
      acc3 = fmaf(wd[3 * KK + k], t3, acc3);
    }
    size_t obase = ((size_t)b * 96 + (cq >> 1)) * HW + (size_t)h * W + w;
    dwp[obase] = ((unsigned)f2bf(acc1) << 16) | (unsigned)f2bf(acc0);
    dwp[obase + HW] = ((unsigned)f2bf(acc3) << 16) | (unsigned)f2bf(acc2);
  }
}

// ---------------------------------------------------------------------------
// Kernel C: pointwise 1x1 conv via bf16 MFMA  [unchanged]
// ---------------------------------------------------------------------------
__global__ __launch_bounds__(256) void pointwise_mfma(
    const unsigned* __restrict__ dwp, const unsigned* __restrict__ wPW,
    float* __restrict__ out) {
  int blk = blockIdx.x;
  int nt = blk & 63;
  int mt = (blk >> 6) % 3;
  int b = blk / 192;
  int n0 = nt * 64;
  int m0 = mt * 128;
  int tid = threadIdx.x;
  int lane = tid & 63;
  int wv = tid >> 6;
  int wm = wv >> 1;
  int wn = wv & 1;
  int lpx = lane & 15;
  int lkg = lane >> 4;

  __shared__ __align__(16) unsigned sA[128 * 22];
  __shared__ __align__(16) unsigned sB[64 * 22];

  f32x4 acc[4][2];
#pragma unroll
  for (int mf = 0; mf < 4; ++mf)
#pragma unroll
    for (int nf = 0; nf < 2; ++nf) acc[mf][nf] = (f32x4){0.f, 0.f, 0.f, 0.f};

  const unsigned* dwb = dwp + (size_t)b * 96 * HW + n0;

  for (int chunk = 0; chunk < 6; ++chunk) {
    int kp0 = chunk * 16;
    __syncthreads();
#pragma unroll
    for (int t = 0; t < 8; ++t) {
      int i = t * 256 + tid;
      int m = i >> 4;
      int cd = i & 15;
      sA[m * 22 + cd] = wPW[(size_t)(m0 + m) * 96 + kp0 + cd];
    }
#pragma unroll
    for (int t = 0; t < 4; ++t) {
      int i = t * 256 + tid;
      int kp = i >> 6;
      int px = i & 63;
      sB[px * 22 + kp] = dwb[(size_t)(kp0 + kp) * HW + px];
    }
    __syncthreads();

    short8 af[4];
#pragma unroll
    for (int mf = 0; mf < 4; ++mf) {
      int m = wm * 64 + mf * 16 + lpx;
      af[mf] = ld_frag8(&sA[m * 22 + lkg * 4]);
    }
    short8 bf[2];
#pragma unroll
    for (int nf = 0; nf < 2; ++nf) {
      int px = wn * 32 + nf * 16 + lpx;
      bf[nf] = ld_frag8(&sB[px * 22 + lkg * 4]);
    }
#pragma unroll
    for (int mf = 0; mf < 4; ++mf)
#pragma unroll
      for (int nf = 0; nf < 2; ++nf)
        acc[mf][nf] = __builtin_amdgcn_mfma_f32_16x16x32_bf16(
            af[mf], bf[nf], acc[mf][nf], 0, 0, 0);
  }

#pragma unroll
  for (int mf = 0; mf < 4; ++mf) {
#pragma unroll
    for (int nf = 0; nf < 2; ++nf) {
      int px = n0 + wn * 32 + nf * 16 + lpx;
#pragma unroll
      for (int j = 0; j < 4; ++j) {
        int o = m0 + wm * 64 + mf * 16 + lkg * 4 + j;
        out[((size_t)b * COUT + o) * HW + px] = acc[mf][nf][j];
      }
    }
  }
}

// ---------------------------------------------------------------------------
extern "C" void kernel_launch(void* const* d_in, const int* in_sizes, int n_in,
                              void* d_out, int out_size, void* d_ws,
                              size_t ws_size, hipStream_t stream) {
  const float* x = (const float*)d_in[0];
  const float* w_off = (const float*)d_in[1];
  const float* b_off = (const float*)d_in[2];
  const float* w_dw = (const float*)d_in[3];
  const float* w_pw = (const float*)d_in[4];
  float* out = (float*)d_out;

  char* ws = (char*)d_ws;
  float* offs = (float*)ws;                       // 4.72 MB
  unsigned* dwp = (unsigned*)(ws + 4718592);      // 25.17 MB
  unsigned short* wA = (unsigned short*)(ws + 4718592 + 25165824);  // 110 KB
  unsigned* wPW = (unsigned*)(ws + 4718592 + 25165824 + 110592);    // 147 KB

  prep_woff<<<(9 * 32 * C + 255) / 256, 256, 0, stream>>>(w_off, wA);
  prep_wpw<<<(COUT * (C / 2) + 255) / 256, 256, 0, stream>>>(w_pw, wPW);
  offset_mfma<<<BB * 16, 256, 0, stream>>>(x, wA, b_off, offs);
  sample_dw<<<BB * 8 * 8, 512, 0, stream>>>(x, offs, w_dw, dwp);
  pointwise_mfma<<<BB * 3 * 64, 256, 0, stream>>>(dwp, wPW, out);
}

// Round 7
// 186.187 us; speedup vs baseline: 4.0977x; 1.0486x over previous
//
#include <hip/hip_runtime.h>

#define BB 16
#define C 192
#define COUT 384
#define H 64
#define W 64
#define HW (H * W)
#define KK 9
#define OFFC 18
#define WROWS 22  // sample_dw staged window rows: [h0-7, h0+15)

typedef __attribute__((ext_vector_type(8))) short short8;
typedef __attribute__((ext_vector_type(4))) float f32x4;

// round-to-nearest-even f32 -> bf16 bits
static __device__ inline unsigned short f2bf(float f) {
  union { float f; unsigned u; } v;
  v.f = f;
  unsigned r = v.u + 0x7FFF + ((v.u >> 16) & 1);
  return (unsigned short)(r >> 16);
}

static __device__ inline float blo(unsigned u) {
  union { unsigned u; float f; } v;
  v.u = u << 16;
  return v.f;
}
static __device__ inline float bhi(unsigned u) {
  union { unsigned u; float f; } v;
  v.u = u & 0xFFFF0000u;
  return v.f;
}

static __device__ inline short8 ld_frag8(const unsigned* p) {
  union { unsigned u[4]; short8 s; } v;
  uint2 a = *(const uint2*)p;
  uint2 b = *(const uint2*)(p + 2);
  v.u[0] = a.x; v.u[1] = a.y; v.u[2] = b.x; v.u[3] = b.y;
  return v.s;
}

// ---------------------------------------------------------------------------
// Prep: wA[k][o(32, zero-padded)][c(192)] bf16 from w_off[o][c][k] f32
// ---------------------------------------------------------------------------
__global__ __launch_bounds__(256) void prep_woff(
    const float* __restrict__ w_off, unsigned short* __restrict__ wA) {
  int idx = blockIdx.x * 256 + threadIdx.x;
  if (idx >= 9 * 32 * C) return;
  int k = idx / (32 * C);
  int rem = idx % (32 * C);
  int o = rem / C;
  int c = rem % C;
  float v = (o < OFFC) ? w_off[((size_t)o * C + c) * KK + k] : 0.f;
  wA[idx] = f2bf(v);
}

// ---------------------------------------------------------------------------
// Prep: wPW[o][cd] packed bf16 c-pairs from w_pw[o][c] f32  (384 x 96 dwords)
// ---------------------------------------------------------------------------
__global__ __launch_bounds__(256) void prep_wpw(
    const float* __restrict__ w_pw, unsigned* __restrict__ wPW) {
  int idx = blockIdx.x * 256 + threadIdx.x;
  if (idx >= COUT * (C / 2)) return;
  float2 v = *(const float2*)(w_pw + (size_t)idx * 2);
  wPW[idx] = ((unsigned)f2bf(v.y) << 16) | (unsigned)f2bf(v.x);
}

// ---------------------------------------------------------------------------
// Kernel A: offset conv via bf16 MFMA, K-split over 6 chunk-blocks.
// grid = B * 16 stripes * 6 chunks = 1536 blocks, 256 thr = 4 waves.
// Each block: one 32-channel chunk; weights loaded per-lane from global
// (wA is L2/L1-resident, 18.4 KB per chunk); x tile staged in LDS (32.6 KB).
// Partials atomicAdd'ed into memset-zeroed offs; chunk 0 adds bias.
// ---------------------------------------------------------------------------
__global__ __launch_bounds__(256) void offset_mfma(
    const float* __restrict__ x, const unsigned short* __restrict__ wA,
    const float* __restrict__ b_off, float* __restrict__ offs) {
  int blk = blockIdx.x;
  int chunk = blk % 6;
  int stripe = (blk / 6) & 15;
  int b = blk / 96;
  int h0 = stripe * 4;
  int c0 = chunk * 32;
  int tid = threadIdx.x;
  int lane = tid & 63;
  int wv = tid >> 6;    // wave id = output row (0..3)
  int lpx = lane & 15;
  int lkg = lane >> 4;

  __shared__ __align__(16) unsigned short xlds[6 * 68 * 40];  // 32640 B

  // zero padding pixel-columns m=0 (col -1) and m=65 (col 64)
  for (int i = tid; i < 6 * 2 * 16; i += 256) {
    int rr = i >> 5;
    int side = (i >> 4) & 1;
    int cd = i & 15;
    int m = side ? 65 : 0;
    ((unsigned*)xlds)[(rr * 68 + m) * 20 + cd] = 0u;
  }

  // stage x tile: rows h0-1..h0+4, cols 0..63 -> m=1..64, 32 ch (16 pairs)
  const float* xb = x + (size_t)b * C * HW;
#pragma unroll
  for (int t = 0; t < 24; ++t) {
    int i = t * 256 + tid;  // 6144 = 16 pairs * 6 rows * 64 cols
    int cc2 = i / 384;
    int rem = i % 384;
    int rr = rem >> 6;
    int col = rem & 63;
    int ly = h0 + rr - 1;
    float a0 = 0.f, a1 = 0.f;
    if (ly >= 0 && ly < H) {
      const float* xp = xb + (size_t)(c0 + 2 * cc2) * HW + ly * W + col;
      a0 = xp[0];
      a1 = xp[HW];
    }
    unsigned pack = ((unsigned)f2bf(a1) << 16) | (unsigned)f2bf(a0);
    ((unsigned*)xlds)[(rr * 68 + col + 1) * 20 + cc2] = pack;
  }

  // A fragments straight from global (L2/L1-resident after first block)
  short8 af[9][2];
#pragma unroll
  for (int k = 0; k < 9; ++k)
#pragma unroll
    for (int m = 0; m < 2; ++m)
      af[k][m] = *(const short8*)(wA + (size_t)(k * 32 + m * 16 + lpx) * C +
                                  c0 + lkg * 8);

  f32x4 acc[4][2];
#pragma unroll
  for (int nt = 0; nt < 4; ++nt)
#pragma unroll
    for (int m = 0; m < 2; ++m) acc[nt][m] = (f32x4){0.f, 0.f, 0.f, 0.f};

  __syncthreads();

#pragma unroll
  for (int nt = 0; nt < 4; ++nt) {
#pragma unroll
    for (int k = 0; k < 9; ++k) {
      int ki = k / 3, kj = k % 3;
      short8 bf =
          *(const short8*)&xlds[((wv + ki) * 68 + nt * 16 + lpx + kj) * 40 +
                                lkg * 8];
      acc[nt][0] = __builtin_amdgcn_mfma_f32_16x16x32_bf16(af[k][0], bf,
                                                           acc[nt][0], 0, 0, 0);
      acc[nt][1] = __builtin_amdgcn_mfma_f32_16x16x32_bf16(af[k][1], bf,
                                                           acc[nt][1], 0, 0, 0);
    }
  }

  // atomic partial-sum epilogue; chunk 0 carries the bias
  int h = h0 + wv;
#pragma unroll
  for (int nt = 0; nt < 4; ++nt) {
    int col = nt * 16 + lpx;
#pragma unroll
    for (int j = 0; j < 4; ++j) {
      int o = lkg * 4 + j;
      float v = acc[nt][0][j] + ((chunk == 0) ? b_off[o] : 0.f);
      atomicAdd(&offs[((size_t)b * OFFC + o) * HW + h * W + col], v);
    }
    if (lkg == 0) {
#pragma unroll
      for (int j = 0; j < 2; ++j) {
        int o2 = 16 + j;
        float v = acc[nt][1][j] + ((chunk == 0) ? b_off[o2] : 0.f);
        atomicAdd(&offs[((size_t)b * OFFC + o2) * HW + h * W + col], v);
      }
    }
  }
}

// ---------------------------------------------------------------------------
// Kernel B: bilinear sample + depthwise -> dwp[B][96][HW] packed bf16 c-pairs
// [unchanged from round 6]
// ---------------------------------------------------------------------------
__global__ __launch_bounds__(512) void sample_dw(
    const float* __restrict__ x, const float* __restrict__ offs,
    const float* __restrict__ w_dw, unsigned* __restrict__ dwp) {
  int blk = blockIdx.x;
  int csplit = blk & 7;
  int rowtile = (blk >> 3) & 7;
  int b = blk >> 6;
  int tid = threadIdx.x;
  int r = tid >> 6;
  int w = tid & 63;
  int h = rowtile * 8 + r;
  int lo = rowtile * 8 - 7;  // window rows [lo, lo+WROWS)

  __shared__ uint2 S[WROWS * 68];  // 11968 B

  for (int i = tid; i < WROWS * 4; i += 512) {
    int rr = i >> 2;
    int p = i & 3;
    int m = (p == 0) ? 0 : 64 + p;
    S[rr * 68 + m] = make_uint2(0u, 0u);
  }

  const float* ob = offs + (size_t)b * OFFC * HW + (size_t)h * W + w;
  int idxA[KK], idxB[KK], gpk[KK];
  float wt[KK][4];
  int okmask = 0;
#pragma unroll
  for (int k = 0; k < KK; ++k) {
    int ki = k / 3, kj = k % 3;
    float oy = ob[(size_t)(2 * k) * HW];
    float ox = ob[(size_t)(2 * k + 1) * HW];
    float py = (float)(h - 1 + ki) + oy;
    float px = (float)(w - 1 + kj) + ox;
    float y0f = floorf(py), x0f = floorf(px);
    float dy = py - y0f, dx = px - x0f;
    int y0 = (int)y0f, x0 = (int)x0f;
    int y1 = y0 + 1, x1 = x0 + 1;
    float vy0 = (y0 >= 0 && y0 < H) ? 1.f : 0.f;
    float vy1 = (y1 >= 0 && y1 < H) ? 1.f : 0.f;
    float vx0 = (x0 >= 0 && x0 < W) ? 1.f : 0.f;
    float vx1 = (x1 >= 0 && x1 < W) ? 1.f : 0.f;
    int y0c = min(max(y0, 0), H - 1);
    int y1c = min(max(y1, 0), H - 1);
    int xc0 = min(max(x0, 0), W - 1);
    int xc1 = min(max(x1, 0), W - 1);
    int xm = min(max(x0, -1), 65) + 1;
    int wy0 = y0c - lo, wy1 = y1c - lo;
    bool ok = ((unsigned)wy0 < WROWS) && ((unsigned)wy1 < WROWS);
    okmask |= ((int)ok) << k;
    idxA[k] = wy0 * 68 + xm;
    idxB[k] = wy1 * 68 + xm;
    gpk[k] = y0c | (y1c << 6) | (xc0 << 12) | (xc1 << 18);
    wt[k][0] = (1.f - dy) * (1.f - dx) * vy0 * vx0;
    wt[k][1] = (1.f - dy) * dx * vy0 * vx1;
    wt[k][2] = dy * (1.f - dx) * vy1 * vx0;
    wt[k][3] = dy * dx * vy1 * vx1;
  }

  const int c0 = csplit * 24;
  const float* xq0 = x + ((size_t)b * C + c0) * HW;

  for (int q = 0; q < 6; ++q) {
    const float* xq = xq0 + (size_t)(q * 4) * HW;
    __syncthreads();
    for (int i = tid; i < WROWS * 64; i += 512) {
      int rr = i >> 6;
      int col = i & 63;
      int ly = lo + rr;
      uint2 p = make_uint2(0u, 0u);
      if (ly >= 0 && ly < H) {
        const float* xp = xq + (size_t)ly * W + col;
        p.x = ((unsigned)f2bf(xp[HW]) << 16) | (unsigned)f2bf(xp[0]);
        p.y = ((unsigned)f2bf(xp[3 * HW]) << 16) | (unsigned)f2bf(xp[2 * HW]);
      }
      S[rr * 68 + col + 1] = p;
    }
    __syncthreads();

    int cq = c0 + q * 4;
    const float* wd = w_dw + (size_t)cq * KK;  // block-uniform -> s_load
    float acc0 = 0.f, acc1 = 0.f, acc2 = 0.f, acc3 = 0.f;
#pragma unroll
    for (int k = 0; k < KK; ++k) {
      float w0 = wt[k][0], w1 = wt[k][1], w2 = wt[k][2], w3 = wt[k][3];
      float t0, t1, t2, t3;
      if (__builtin_expect((okmask >> k) & 1, 1)) {
        uint2 u00 = S[idxA[k]], u01 = S[idxA[k] + 1];
        uint2 u10 = S[idxB[k]], u11 = S[idxB[k] + 1];
        t0 = fmaf(w3, blo(u11.x),
             fmaf(w2, blo(u10.x), fmaf(w1, blo(u01.x), w0 * blo(u00.x))));
        t1 = fmaf(w3, bhi(u11.x),
             fmaf(w2, bhi(u10.x), fmaf(w1, bhi(u01.x), w0 * bhi(u00.x))));
        t2 = fmaf(w3, blo(u11.y),
             fmaf(w2, blo(u10.y), fmaf(w1, blo(u01.y), w0 * blo(u00.y))));
        t3 = fmaf(w3, bhi(u11.y),
             fmaf(w2, bhi(u10.y), fmaf(w1, bhi(u01.y), w0 * bhi(u00.y))));
      } else {
        int g = gpk[k];
        int a00 = (g & 63) * W + ((g >> 12) & 63);
        int a01 = (g & 63) * W + ((g >> 18) & 63);
        int a10 = ((g >> 6) & 63) * W + ((g >> 12) & 63);
        int a11 = ((g >> 6) & 63) * W + ((g >> 18) & 63);
        const float* p0 = xq;
        const float* p1 = xq + HW;
        const float* p2 = xq + 2 * HW;
        const float* p3 = xq + 3 * HW;
        t0 = fmaf(w3, p0[a11], fmaf(w2, p0[a10], fmaf(w1, p0[a01], w0 * p0[a00])));
        t1 = fmaf(w3, p1[a11], fmaf(w2, p1[a10], fmaf(w1, p1[a01], w0 * p1[a00])));
        t2 = fmaf(w3, p2[a11], fmaf(w2, p2[a10], fmaf(w1, p2[a01], w0 * p2[a00])));
        t3 = fmaf(w3, p3[a11], fmaf(w2, p3[a10], fmaf(w1, p3[a01], w0 * p3[a00])));
      }
      acc0 = fmaf(wd[k], t0, acc0);
      acc1 = fmaf(wd[KK + k], t1, acc1);
      acc2 = fmaf(wd[2 * KK + k], t2, acc2);
      acc3 = fmaf(wd[3 * KK + k], t3, acc3);
    }
    size_t obase = ((size_t)b * 96 + (cq >> 1)) * HW + (size_t)h * W + w;
    dwp[obase] = ((unsigned)f2bf(acc1) << 16) | (unsigned)f2bf(acc0);
    dwp[obase + HW] = ((unsigned)f2bf(acc3) << 16) | (unsigned)f2bf(acc2);
  }
}

// ---------------------------------------------------------------------------
// Kernel C: pointwise 1x1 conv via bf16 MFMA  [unchanged]
// ---------------------------------------------------------------------------
__global__ __launch_bounds__(256) void pointwise_mfma(
    const unsigned* __restrict__ dwp, const unsigned* __restrict__ wPW,
    float* __restrict__ out) {
  int blk = blockIdx.x;
  int nt = blk & 63;
  int mt = (blk >> 6) % 3;
  int b = blk / 192;
  int n0 = nt * 64;
  int m0 = mt * 128;
  int tid = threadIdx.x;
  int lane = tid & 63;
  int wv = tid >> 6;
  int wm = wv >> 1;
  int wn = wv & 1;
  int lpx = lane & 15;
  int lkg = lane >> 4;

  __shared__ __align__(16) unsigned sA[128 * 22];
  __shared__ __align__(16) unsigned sB[64 * 22];

  f32x4 acc[4][2];
#pragma unroll
  for (int mf = 0; mf < 4; ++mf)
#pragma unroll
    for (int nf = 0; nf < 2; ++nf) acc[mf][nf] = (f32x4){0.f, 0.f, 0.f, 0.f};

  const unsigned* dwb = dwp + (size_t)b * 96 * HW + n0;

  for (int chunk = 0; chunk < 6; ++chunk) {
    int kp0 = chunk * 16;
    __syncthreads();
#pragma unroll
    for (int t = 0; t < 8; ++t) {
      int i = t * 256 + tid;
      int m = i >> 4;
      int cd = i & 15;
      sA[m * 22 + cd] = wPW[(size_t)(m0 + m) * 96 + kp0 + cd];
    }
#pragma unroll
    for (int t = 0; t < 4; ++t) {
      int i = t * 256 + tid;
      int kp = i >> 6;
      int px = i & 63;
      sB[px * 22 + kp] = dwb[(size_t)(kp0 + kp) * HW + px];
    }
    __syncthreads();

    short8 af[4];
#pragma unroll
    for (int mf = 0; mf < 4; ++mf) {
      int m = wm * 64 + mf * 16 + lpx;
      af[mf] = ld_frag8(&sA[m * 22 + lkg * 4]);
    }
    short8 bf[2];
#pragma unroll
    for (int nf = 0; nf < 2; ++nf) {
      int px = wn * 32 + nf * 16 + lpx;
      bf[nf] = ld_frag8(&sB[px * 22 + lkg * 4]);
    }
#pragma unroll
    for (int mf = 0; mf < 4; ++mf)
#pragma unroll
      for (int nf = 0; nf < 2; ++nf)
        acc[mf][nf] = __builtin_amdgcn_mfma_f32_16x16x32_bf16(
            af[mf], bf[nf], acc[mf][nf], 0, 0, 0);
  }

#pragma unroll
  for (int mf = 0; mf < 4; ++mf) {
#pragma unroll
    for (int nf = 0; nf < 2; ++nf) {
      int px = n0 + wn * 32 + nf * 16 + lpx;
#pragma unroll
      for (int j = 0; j < 4; ++j) {
        int o = m0 + wm * 64 + mf * 16 + lkg * 4 + j;
        out[((size_t)b * COUT + o) * HW + px] = acc[mf][nf][j];
      }
    }
  }
}

// ---------------------------------------------------------------------------
extern "C" void kernel_launch(void* const* d_in, const int* in_sizes, int n_in,
                              void* d_out, int out_size, void* d_ws,
                              size_t ws_size, hipStream_t stream) {
  const float* x = (const float*)d_in[0];
  const float* w_off = (const float*)d_in[1];
  const float* b_off = (const float*)d_in[2];
  const float* w_dw = (const float*)d_in[3];
  const float* w_pw = (const float*)d_in[4];
  float* out = (float*)d_out;

  char* ws = (char*)d_ws;
  float* offs = (float*)ws;                       // 4.72 MB
  unsigned* dwp = (unsigned*)(ws + 4718592);      // 25.17 MB
  unsigned short* wA = (unsigned short*)(ws + 4718592 + 25165824);  // 110 KB
  unsigned* wPW = (unsigned*)(ws + 4718592 + 25165824 + 110592);    // 147 KB

  hipMemsetAsync(offs, 0, (size_t)BB * OFFC * HW * sizeof(float), stream);
  prep_woff<<<(9 * 32 * C + 255) / 256, 256, 0, stream>>>(w_off, wA);
  prep_wpw<<<(COUT * (C / 2) + 255) / 256, 256, 0, stream>>>(w_pw, wPW);
  offset_mfma<<<BB * 16 * 6, 256, 0, stream>>>(x, wA, b_off, offs);
  sample_dw<<<BB * 8 * 8, 512, 0, stream>>>(x, offs, w_dw, dwp);
  pointwise_mfma<<<BB * 3 * 64, 256, 0, stream>>>(dwp, wPW, out);
}